// Round 8
// baseline (635.532 us; speedup 1.0000x reference)
//
#include <hip/hip_runtime.h>
#include <math.h>

// B=2, S=2048, H=2048, NH=16, KVH=4, D=128, layer 5.
// GEMMs: mfma_f32_16x16x32_bf16, 128x128 tile, in-block split-K (R9) with
//   v14 PARALLEL merge epilogue (both groups publish half / finalize half).
// Attention v14 = v12 base (best: 60.6us, 3 waves/SIMD) +
//   - QK chain split: St0(ks0-3) || St1(ks4-7), halves the 8-deep
//     dependent MFMA chain per iteration,
//   - s_setprio(1) around MFMA clusters (T5; attn-positive regime:
//     barrier-free waves at diverse phases).
// Launches: prep_all -> GEMM1(packed-Q) -> attn(+wp cvt) -> GEMM2.

#define RSQ128 0.08838834764831845
#define LOG2E  1.4426950408889634
#define RS2L   ((float)(RSQ128 * LOG2E))
#define CAP2   24.0f

typedef __attribute__((ext_vector_type(8))) short short8;    // 8 bf16 = 4 VGPR
typedef __attribute__((ext_vector_type(4))) float f32x4;     // 16x16 C/D
typedef __attribute__((ext_vector_type(16))) float f32x16;   // 32x32 C/D

static __device__ __forceinline__ unsigned short f2bf(float x) {
    union { float f; unsigned u; } v; v.f = x;
    unsigned r = v.u + 0x7FFFu + ((v.u >> 16) & 1u);   // RNE
    return (unsigned short)(r >> 16);
}

static __device__ __forceinline__ unsigned pack_bf16(float lo, float hi) {
#if __has_builtin(__builtin_amdgcn_cvt_pk_bf16_f32)
    return __builtin_bit_cast(unsigned, __builtin_amdgcn_cvt_pk_bf16_f32(lo, hi));
#else
    return (unsigned)f2bf(lo) | ((unsigned)f2bf(hi) << 16);
#endif
}

static __device__ __forceinline__ float fexp2(float x) {
#if __has_builtin(__builtin_amdgcn_exp2f)
    return __builtin_amdgcn_exp2f(x);
#else
    return exp2f(x);
#endif
}

static __device__ __forceinline__ void gl_lds16(const void* g, void* l) {
    __builtin_amdgcn_global_load_lds(
        (const __attribute__((address_space(1))) void*)g,
        (__attribute__((address_space(3))) void*)l, 16, 0, 0);
}

static __device__ __forceinline__ void cvt8(const float* __restrict__ in,
                                            unsigned short* __restrict__ out,
                                            int i) {
    const float4 a = *(const float4*)(in + i);
    const float4 b = *(const float4*)(in + i + 4);
    short8 o;
    o[0] = (short)f2bf(a.x); o[1] = (short)f2bf(a.y);
    o[2] = (short)f2bf(a.z); o[3] = (short)f2bf(a.w);
    o[4] = (short)f2bf(b.x); o[5] = (short)f2bf(b.y);
    o[6] = (short)f2bf(b.z); o[7] = (short)f2bf(b.w);
    *(short8*)(out + i) = o;
}

// ---------------------------------------------------------------------------
// prep_all: one launch for {hs cvt, wq cvt, K prepack, V prepack}.
// blocks [0,4096): hs | [4096,6144): wq | [6144,6656): kprep | [6656,7168): vprep
// ---------------------------------------------------------------------------
__global__ void prep_all(const float* __restrict__ hs, unsigned short* __restrict__ hsb,
                         const float* __restrict__ wq, unsigned short* __restrict__ wqb,
                         const float* __restrict__ K,  unsigned short* __restrict__ Kpk,
                         const float* __restrict__ V,  unsigned short* __restrict__ Vpk)
{
    __shared__ float Ts[32][132];
    const int bid = blockIdx.x, tid = threadIdx.x;

    if (bid < 4096) {                       // hs: 8,388,608 elems
        cvt8(hs, hsb, (bid * 256 + tid) * 8);
        return;
    }
    if (bid < 6144) {                       // wq: 4,194,304 elems
        cvt8(wq, wqb, ((bid - 4096) * 256 + tid) * 8);
        return;
    }
    if (bid < 6656) {                       // kprep: [8][64 tiles]
        const int idx = bid - 6144;
        const int t = idx & 63, bkh = idx >> 6;
        const float* src = K + ((size_t)bkh * 2048 + t * 32) * 128;
        unsigned short* dst = Kpk + ((size_t)bkh * 64 + t) * 4096;
#pragma unroll
        for (int p = 0; p < 2; ++p) {
            const int g = p * 256 + tid;
            const int ch = g >> 5, key = g & 31;
            const float4 a = *(const float4*)(src + key * 128 + ch * 8);
            const float4 b = *(const float4*)(src + key * 128 + ch * 8 + 4);
            short8 o;
            o[0] = (short)f2bf(a.x); o[1] = (short)f2bf(a.y);
            o[2] = (short)f2bf(a.z); o[3] = (short)f2bf(a.w);
            o[4] = (short)f2bf(b.x); o[5] = (short)f2bf(b.y);
            o[6] = (short)f2bf(b.z); o[7] = (short)f2bf(b.w);
            *(short8*)(dst + ch * 256 + key * 8) = o;
        }
        return;
    }
    {                                       // vprep: [8][64 tiles]
        const int idx = bid - 6656;
        const int t = idx & 63, bkh = idx >> 6;
        const float* src = V + ((size_t)bkh * 2048 + t * 32) * 128;
        unsigned short* dst = Vpk + ((size_t)bkh * 64 + t) * 4096;
#pragma unroll
        for (int p = 0; p < 4; ++p) {
            const int g = p * 256 + tid;
            const int key = g >> 5, cq = g & 31;
            const float4 v = *(const float4*)(src + key * 128 + cq * 4);
            *(float4*)&Ts[key][cq * 4] = v;
        }
        __syncthreads();
#pragma unroll
        for (int p = 0; p < 2; ++p) {
            const int g = p * 256 + tid;
            const int kc = g >> 7, d = g & 127;
            short8 o;
#pragma unroll
            for (int j = 0; j < 8; ++j) o[j] = (short)f2bf(Ts[kc * 8 + j][d]);
            *(short8*)(dst + kc * 1024 + d * 8) = o;
        }
    }
}

// ---------------------------------------------------------------------------
// NT GEMM bf16 MFMA, 128x128 tile, in-block split-K (R9) + parallel epilogue.
// OMODE: 0 = fp32 row-major, 2 = bf16 packed-Q layout
//        ([b][h][qtile32][16 ch][32 q][8] — K-fragment layout for attn).
// ---------------------------------------------------------------------------
template <int OMODE>
__global__ __launch_bounds__(512, 2) void gemm_nt_sk(
    const unsigned short* __restrict__ A,
    const unsigned short* __restrict__ W,
    const float* __restrict__ bias,
    void* __restrict__ Cout, int M, int N, int K, float oscale)
{
    __shared__ __align__(16) unsigned short SMEM[32768];   // 64 KB
    unsigned short* Asb = SMEM;
    unsigned short* Wsb = SMEM + 16384;

    const int tid = threadIdx.x;
    const int g = tid >> 8;
    const int t2 = tid & 255;
    const int lane = tid & 63;
    const int wq = (tid >> 6) & 3;
    const int wm = wq & 1, wn = wq >> 1;
    const int m0 = blockIdx.y * 128, n0 = blockIdx.x * 128;
    const int r0 = t2 >> 2, c0 = t2 & 3;
    const int Kh = K >> 1;

    const unsigned short* Ag = A + (size_t)(m0 + r0) * K + g * Kh + c0 * 8;
    const unsigned short* Wg = W + (size_t)(n0 + r0) * K + g * Kh + c0 * 8;

    f32x4 acc[4][4];
#pragma unroll
    for (int i = 0; i < 4; ++i)
#pragma unroll
        for (int j = 0; j < 4; ++j) acc[i][j] = (f32x4){0.f, 0.f, 0.f, 0.f};

    const int lm = lane & 15, lk = (lane >> 4) * 8;
    unsigned short* As0 = Asb + g * 8192;
    unsigned short* Ws0 = Wsb + g * 8192;

    gl_lds16(Ag,                  As0 + t2 * 8);
    gl_lds16(Ag + (size_t)64 * K, As0 + (t2 + 256) * 8);
    gl_lds16(Wg,                  Ws0 + t2 * 8);
    gl_lds16(Wg + (size_t)64 * K, Ws0 + (t2 + 256) * 8);

    int buf = 0;
    for (int k0 = 0; k0 < Kh; k0 += 32) {
        __syncthreads();
        const int kn = k0 + 32;
        if (kn < Kh) {
            unsigned short* Ad = As0 + (buf ^ 1) * 4096;
            unsigned short* Wd = Ws0 + (buf ^ 1) * 4096;
            gl_lds16(Ag + kn,                  Ad + t2 * 8);
            gl_lds16(Ag + (size_t)64 * K + kn, Ad + (t2 + 256) * 8);
            gl_lds16(Wg + kn,                  Wd + t2 * 8);
            gl_lds16(Wg + (size_t)64 * K + kn, Wd + (t2 + 256) * 8);
        }

        const unsigned short* Ar = As0 + buf * 4096;
        const unsigned short* Wr = Ws0 + buf * 4096;
        short8 a[4], b[4];
#pragma unroll
        for (int i = 0; i < 4; ++i)
            a[i] = *(const short8*)&Ar[(64 * wm + 16 * i + lm) * 32 + lk];
#pragma unroll
        for (int j = 0; j < 4; ++j)
            b[j] = *(const short8*)&Wr[(64 * wn + 16 * j + lm) * 32 + lk];
#pragma unroll
        for (int i = 0; i < 4; ++i)
#pragma unroll
            for (int j = 0; j < 4; ++j)
                acc[i][j] = __builtin_amdgcn_mfma_f32_16x16x32_bf16(a[i], b[j], acc[i][j], 0, 0, 0);
        buf ^= 1;
    }

    // ---- v14 parallel split-K merge: each group publishes the half the
    //      OTHER group finalizes, then both groups finalize concurrently.
    //      g=0 finalizes rows i in {0,1}; g=1 finalizes i in {2,3}.
    float* MRG = (float*)SMEM;   // 16384 floats = 64 KB, split g*8192
    __syncthreads();
    {
        const int ipub = (g == 0) ? 2 : 0;   // tiles this group publishes
#pragma unroll
        for (int ii = 0; ii < 2; ++ii)
#pragma unroll
            for (int j = 0; j < 4; ++j) {
                const int i = ipub + ii;
                float4 v4;
                v4.x = acc[i][j][0]; v4.y = acc[i][j][1];
                v4.z = acc[i][j][2]; v4.w = acc[i][j][3];
                *(float4*)&MRG[g * 8192 + ((ii * 4 + j) * 256 + wq * 64 + lane) * 4] = v4;
            }
    }
    __syncthreads();
    {
        const int ifin = (g == 0) ? 0 : 2;   // tiles this group finalizes
        const float* src = MRG + (g ^ 1) * 8192;
        float bv[4];
#pragma unroll
        for (int j = 0; j < 4; ++j) bv[j] = bias[n0 + 64 * wn + 16 * j + lm];
#pragma unroll
        for (int ii = 0; ii < 2; ++ii)
#pragma unroll
            for (int j = 0; j < 4; ++j) {
                const int i = ifin + ii;
                const float4 v4 = *(const float4*)&src[((ii * 4 + j) * 256 + wq * 64 + lane) * 4];
                const float s[4] = {v4.x, v4.y, v4.z, v4.w};
#pragma unroll
                for (int reg = 0; reg < 4; ++reg) {
                    const int row = m0 + 64 * wm + 16 * i + 4 * (lane >> 4) + reg;
                    const int col = n0 + 64 * wn + 16 * j + lm;
                    const float v = (acc[i][j][reg] + s[reg] + bv[j]) * oscale;
                    if (OMODE == 0) {
                        ((float*)Cout)[(size_t)row * N + col] = v;
                    } else {
                        // packed-Q: row=(b,s), col=(h,d) -> [(b*16+h)*64 + s/32][d/8][s%32][d%8]
                        const int bb = row >> 11, ss = row & 2047;
                        const int hh = col >> 7, dd = col & 127;
                        const size_t o = (size_t)((bb * 16 + hh) * 64 + (ss >> 5)) * 4096
                                       + (dd >> 3) * 256 + (ss & 31) * 8 + (dd & 7);
                        ((unsigned short*)Cout)[o] = f2bf(v);
                    }
                }
            }
    }
}

// ---------------------------------------------------------------------------
// Flash attention v14: v12 base + QK chain split + setprio MFMA clusters.
// 128-thr blocks (2 key-parity waves, one 32-row q-tile), Q in LDS,
// K/V register-direct. Blocks [2048, 6144): fused wp fp32->bf16 convert.
// ---------------------------------------------------------------------------
__global__ __launch_bounds__(128, 3) void attn_mfma14(
    const unsigned short* __restrict__ Qpk, // [2][16][64][16][32][8] bf16, pre-scaled
    const unsigned short* __restrict__ Kpk, // [8][64][16][32][8] bf16
    const unsigned short* __restrict__ Vpk, // [8][64][4][128][8] bf16
    unsigned short* __restrict__ O,         // [4096][2048] bf16
    const float* __restrict__ wp,           // fused: wp cvt input
    unsigned short* __restrict__ wpb)       // fused: wp cvt output
{
    __shared__ __align__(16) float MRG[4096];   // 16 KB: Q tile / merge / epilogue
    __shared__ float Lsm[64];

    const int tid = threadIdx.x;

    if (blockIdx.x >= 2048) {               // fused wp convert
        const int i = ((blockIdx.x - 2048) * 128 + tid) * 8;
        cvt8(wp, wpb, i);
        return;
    }

    const int lane = tid & 63, pz = tid >> 6;
    const int h2 = lane >> 5, ln = lane & 31;

    // bid&7 = (b,kh): one K/V set per XCD (L2-local). Long q-tiles first.
    const int bid = blockIdx.x;
    const int grp = bid & 7;
    const int idx = bid >> 3;               // [0,256)
    const int b = grp >> 2, kh = grp & 3;
    const int hl = idx & 3;
    const int qt = 63 - (idx >> 2);         // [0,64), descending work
    const int h = kh * 4 + hl;

    const unsigned short* Kbase = Kpk + (size_t)(b * 4 + kh) * 64 * 4096;
    const unsigned short* Vbase = Vpk + (size_t)(b * 4 + kh) * 64 * 4096;
    const int koff = h2 * 256 + ln * 8;     // K fragment lane offset (shorts)
    const int voff = h2 * 1024 + ln * 8;    // V fragment lane offset (shorts)

    // ---- stage Q tile (8 KB) into LDS, fragment layout ----
    unsigned short* QL = (unsigned short*)MRG;
    {
        const unsigned short* qsrc = Qpk + (size_t)((b * 16 + h) * 64 + qt) * 4096;
#pragma unroll
        for (int i = 0; i < 4; ++i)
            gl_lds16(qsrc + (i * 128 + tid) * 8, QL + (i * 128 + pz * 64) * 8);
    }

    f32x16 Ot[4];
#pragma unroll
    for (int mt = 0; mt < 4; ++mt)
#pragma unroll
        for (int r = 0; r < 16; ++r) Ot[mt][r] = 0.f;
    float l_ = 0.f;

    __syncthreads();   // Q staged (vmcnt drained by syncthreads)

    const int q_lo = qt * 32;
    const int qg = q_lo + ln;
    const int q_hi = q_lo + 31;
    const int jmax = qt >> 1;

    for (int j = 0; j <= jmax; ++j) {
        const int t0 = 64 * j + 32 * pz;
        if (t0 > q_hi) continue;     // only pz=1 at j==jmax for even qt

        const unsigned short* Kt = Kbase + (size_t)(2 * j + pz) * 4096;
        const unsigned short* Vt = Vbase + (size_t)(2 * j + pz) * 4096;

        short8 kf[8], vf[8];
#pragma unroll
        for (int ks = 0; ks < 8; ++ks)
            kf[ks] = *(const short8*)(Kt + ks * 512 + koff);
#pragma unroll
        for (int i = 0; i < 8; ++i)
            vf[i] = *(const short8*)(Vt + (i >> 2) * 2048 + (i & 3) * 256 + voff);

        // ---- St = K Q^T, TWO independent 4-deep chains (St0 || St1) ----
        f32x16 St0, St1;
#pragma unroll
        for (int r = 0; r < 16; ++r) { St0[r] = 0.f; St1[r] = 0.f; }
        __builtin_amdgcn_s_setprio(1);
#pragma unroll
        for (int ks = 0; ks < 4; ++ks) {
            const short8 qa = *(const short8*)(QL + ks * 512 + h2 * 256 + ln * 8);
            St0 = __builtin_amdgcn_mfma_f32_32x32x16_bf16(kf[ks], qa, St0, 0, 0, 0);
            const short8 qb = *(const short8*)(QL + (ks + 4) * 512 + h2 * 256 + ln * 8);
            St1 = __builtin_amdgcn_mfma_f32_32x32x16_bf16(kf[ks + 4], qb, St1, 0, 0, 0);
        }
        __builtin_amdgcn_s_setprio(0);

        // ---- P = exp2(s - CAP) with causal mask; row sum ----
        float s_loc = 0.f;
        unsigned Pp[8];
        if (t0 + 31 <= q_lo) {   // wave fully unmasked
#pragma unroll
            for (int p = 0; p < 8; ++p) {
                const float p0 = fexp2(St0[2 * p] + St1[2 * p] - CAP2);
                const float p1 = fexp2(St0[2 * p + 1] + St1[2 * p + 1] - CAP2);
                s_loc += p0 + p1;
                Pp[p] = pack_bf16(p0, p1);
            }
        } else {
#pragma unroll
            for (int p = 0; p < 8; ++p) {
                const int k0 = t0 + (2 * p & 3) + 8 * (2 * p >> 2) + 4 * h2;
                const int k1 = t0 + ((2 * p + 1) & 3) + 8 * ((2 * p + 1) >> 2) + 4 * h2;
                const float p0 = (k0 <= qg) ? fexp2(St0[2 * p] + St1[2 * p] - CAP2) : 0.f;
                const float p1 = (k1 <= qg) ? fexp2(St0[2 * p + 1] + St1[2 * p + 1] - CAP2) : 0.f;
                s_loc += p0 + p1;
                Pp[p] = pack_bf16(p0, p1);
            }
        }
        s_loc += __shfl_xor(s_loc, 32);
        l_ += s_loc;

        // ---- Ot += V P^T (2 k-steps of 16 keys; 4 indep acc chains) ----
#pragma unroll
        for (int ks4 = 0; ks4 < 2; ++ks4) {
            const unsigned pa = Pp[4 * ks4 + 0], pb = Pp[4 * ks4 + 1];
            const unsigned pc = Pp[4 * ks4 + 2], pd = Pp[4 * ks4 + 3];
            const unsigned x0 = (unsigned)__shfl_xor((int)(h2 ? pa : pc), 32);
            const unsigned x1 = (unsigned)__shfl_xor((int)(h2 ? pb : pd), 32);
            union { unsigned u[4]; short8 s8; } fr;
            fr.u[0] = h2 ? x0 : pa;
            fr.u[1] = h2 ? x1 : pb;
            fr.u[2] = h2 ? pc : x0;
            fr.u[3] = h2 ? pd : x1;
            __builtin_amdgcn_s_setprio(1);
#pragma unroll
            for (int mt = 0; mt < 4; ++mt)
                Ot[mt] = __builtin_amdgcn_mfma_f32_32x32x16_bf16(vf[ks4 * 4 + mt], fr.s8, Ot[mt], 0, 0, 0);
            __builtin_amdgcn_s_setprio(0);
        }
    }

    // ---- merge key-parity states: plain add (same CAP both halves) ----
    __syncthreads();   // Q reads done; MRG reusable
    if (pz == 1) {
#pragma unroll
        for (int mt = 0; mt < 4; ++mt)
#pragma unroll
            for (int g = 0; g < 4; ++g) {
                float4 v4;
                v4.x = Ot[mt][4 * g + 0]; v4.y = Ot[mt][4 * g + 1];
                v4.z = Ot[mt][4 * g + 2]; v4.w = Ot[mt][4 * g + 3];
                *(float4*)&MRG[lane * 64 + (((mt * 4 + g + lane) & 15) * 4)] = v4;
            }
        Lsm[lane] = l_;
    }
    __syncthreads();
    if (pz == 0) {
        l_ += Lsm[lane];
#pragma unroll
        for (int mt = 0; mt < 4; ++mt)
#pragma unroll
            for (int g = 0; g < 4; ++g) {
                const float4 v4 = *(const float4*)&MRG[lane * 64 + (((mt * 4 + g + lane) & 15) * 4)];
                Ot[mt][4 * g + 0] += v4.x;
                Ot[mt][4 * g + 1] += v4.y;
                Ot[mt][4 * g + 2] += v4.z;
                Ot[mt][4 * g + 3] += v4.w;
            }
    }
    __syncthreads();

    if (pz == 0) {
        unsigned short* Es = (unsigned short*)MRG;
        const float inv = 1.0f / l_;
#pragma unroll
        for (int mt = 0; mt < 4; ++mt)
#pragma unroll
            for (int g = 0; g < 4; ++g) {
                uint2 pk;
                pk.x = pack_bf16(Ot[mt][4 * g + 0] * inv, Ot[mt][4 * g + 1] * inv);
                pk.y = pack_bf16(Ot[mt][4 * g + 2] * inv, Ot[mt][4 * g + 3] * inv);
                const int chunk = (4 * mt + g) ^ (ln & 15);
                *(uint2*)&Es[ln * 128 + chunk * 8 + 4 * h2] = pk;
            }
    }
    __syncthreads();
    if (pz == 0) {
        unsigned short* Es = (unsigned short*)MRG;
#pragma unroll
        for (int pp = 0; pp < 8; ++pp) {
            const int f = pp * 64 + lane;
            const int q = f >> 4, c = f & 15;
            const short8 v = *(const short8*)&Es[q * 128 + ((c ^ (q & 15)) * 8)];
            *(short8*)(O + (size_t)(b * 2048 + q_lo + q) * 2048 + h * 128 + c * 8) = v;
        }
    }
}

// ---------------------------------------------------------------------------
extern "C" void kernel_launch(void* const* d_in, const int* in_sizes, int n_in,
                              void* d_out, int out_size, void* d_ws, size_t ws_size,
                              hipStream_t stream) {
    const float* hs = (const float*)d_in[0];
    const float* k  = (const float*)d_in[1];
    const float* v  = (const float*)d_in[2];
    const float* wq = (const float*)d_in[3];
    const float* bq = (const float*)d_in[4];
    const float* wp = (const float*)d_in[5];
    const float* bp = (const float*)d_in[6];
    float* out = (float*)d_out;

    unsigned short* hsb  = (unsigned short*)d_ws;     // 8,388,608
    unsigned short* wqb  = hsb  + 8388608;            // 4,194,304
    unsigned short* kpk  = wqb  + 4194304;            // 2,097,152
    unsigned short* vpk  = kpk  + 2097152;            // 2,097,152
    unsigned short* qbuf = vpk  + 2097152;            // 8,388,608 (packed Q)
    unsigned short* abuf = qbuf + 8388608;            // 8,388,608
    unsigned short* wpb  = hsb;                       // alias (hs dead after GEMM1)

    prep_all<<<7168, 256, 0, stream>>>(hs, hsb, wq, wqb, k, kpk, v, vpk);

    dim3 gG(16, 32);
    gemm_nt_sk<2><<<gG, 512, 0, stream>>>(hsb, wqb, bq, qbuf, 4096, 2048, 2048, RS2L);
    attn_mfma14<<<6144, 128, 0, stream>>>(qbuf, kpk, vpk, abuf, wp, wpb);
    gemm_nt_sk<0><<<gG, 512, 0, stream>>>(abuf, wpb, bp, out, 4096, 2048, 2048, 1.0f);
}

// Round 9
// 320.836 us; speedup vs baseline: 1.9809x; 1.9809x over previous
//
#include <hip/hip_runtime.h>
#include <math.h>

// B=2, S=2048, H=2048, NH=16, KVH=4, D=128, layer 5.
// GEMMs: mfma_f32_16x16x32_bf16, 128x128 tile, in-block split-K (R9 epilogue,
//   STATIC acc indexing only — R8's runtime-indexed epilogue scratch-spilled
//   the accumulator: VGPR 120->56, WRITE_SIZE 2MB->2.2GB, 58->352us).
// Attention v14 (kept, delta measurable this round): v12 base +
//   QK chain split (St0||St1) + s_setprio around MFMA clusters.
// Launches: prep_all -> GEMM1(packed-Q) -> attn(+wp cvt) -> GEMM2.

#define RSQ128 0.08838834764831845
#define LOG2E  1.4426950408889634
#define RS2L   ((float)(RSQ128 * LOG2E))
#define CAP2   24.0f

typedef __attribute__((ext_vector_type(8))) short short8;    // 8 bf16 = 4 VGPR
typedef __attribute__((ext_vector_type(4))) float f32x4;     // 16x16 C/D
typedef __attribute__((ext_vector_type(16))) float f32x16;   // 32x32 C/D

static __device__ __forceinline__ unsigned short f2bf(float x) {
    union { float f; unsigned u; } v; v.f = x;
    unsigned r = v.u + 0x7FFFu + ((v.u >> 16) & 1u);   // RNE
    return (unsigned short)(r >> 16);
}

static __device__ __forceinline__ unsigned pack_bf16(float lo, float hi) {
#if __has_builtin(__builtin_amdgcn_cvt_pk_bf16_f32)
    return __builtin_bit_cast(unsigned, __builtin_amdgcn_cvt_pk_bf16_f32(lo, hi));
#else
    return (unsigned)f2bf(lo) | ((unsigned)f2bf(hi) << 16);
#endif
}

static __device__ __forceinline__ float fexp2(float x) {
#if __has_builtin(__builtin_amdgcn_exp2f)
    return __builtin_amdgcn_exp2f(x);
#else
    return exp2f(x);
#endif
}

static __device__ __forceinline__ void gl_lds16(const void* g, void* l) {
    __builtin_amdgcn_global_load_lds(
        (const __attribute__((address_space(1))) void*)g,
        (__attribute__((address_space(3))) void*)l, 16, 0, 0);
}

static __device__ __forceinline__ void cvt8(const float* __restrict__ in,
                                            unsigned short* __restrict__ out,
                                            int i) {
    const float4 a = *(const float4*)(in + i);
    const float4 b = *(const float4*)(in + i + 4);
    short8 o;
    o[0] = (short)f2bf(a.x); o[1] = (short)f2bf(a.y);
    o[2] = (short)f2bf(a.z); o[3] = (short)f2bf(a.w);
    o[4] = (short)f2bf(b.x); o[5] = (short)f2bf(b.y);
    o[6] = (short)f2bf(b.z); o[7] = (short)f2bf(b.w);
    *(short8*)(out + i) = o;
}

// ---------------------------------------------------------------------------
// prep_all: one launch for {hs cvt, wq cvt, K prepack, V prepack}.
// blocks [0,4096): hs | [4096,6144): wq | [6144,6656): kprep | [6656,7168): vprep
// ---------------------------------------------------------------------------
__global__ void prep_all(const float* __restrict__ hs, unsigned short* __restrict__ hsb,
                         const float* __restrict__ wq, unsigned short* __restrict__ wqb,
                         const float* __restrict__ K,  unsigned short* __restrict__ Kpk,
                         const float* __restrict__ V,  unsigned short* __restrict__ Vpk)
{
    __shared__ float Ts[32][132];
    const int bid = blockIdx.x, tid = threadIdx.x;

    if (bid < 4096) {                       // hs: 8,388,608 elems
        cvt8(hs, hsb, (bid * 256 + tid) * 8);
        return;
    }
    if (bid < 6144) {                       // wq: 4,194,304 elems
        cvt8(wq, wqb, ((bid - 4096) * 256 + tid) * 8);
        return;
    }
    if (bid < 6656) {                       // kprep: [8][64 tiles]
        const int idx = bid - 6144;
        const int t = idx & 63, bkh = idx >> 6;
        const float* src = K + ((size_t)bkh * 2048 + t * 32) * 128;
        unsigned short* dst = Kpk + ((size_t)bkh * 64 + t) * 4096;
#pragma unroll
        for (int p = 0; p < 2; ++p) {
            const int g = p * 256 + tid;
            const int ch = g >> 5, key = g & 31;
            const float4 a = *(const float4*)(src + key * 128 + ch * 8);
            const float4 b = *(const float4*)(src + key * 128 + ch * 8 + 4);
            short8 o;
            o[0] = (short)f2bf(a.x); o[1] = (short)f2bf(a.y);
            o[2] = (short)f2bf(a.z); o[3] = (short)f2bf(a.w);
            o[4] = (short)f2bf(b.x); o[5] = (short)f2bf(b.y);
            o[6] = (short)f2bf(b.z); o[7] = (short)f2bf(b.w);
            *(short8*)(dst + ch * 256 + key * 8) = o;
        }
        return;
    }
    {                                       // vprep: [8][64 tiles]
        const int idx = bid - 6656;
        const int t = idx & 63, bkh = idx >> 6;
        const float* src = V + ((size_t)bkh * 2048 + t * 32) * 128;
        unsigned short* dst = Vpk + ((size_t)bkh * 64 + t) * 4096;
#pragma unroll
        for (int p = 0; p < 4; ++p) {
            const int g = p * 256 + tid;
            const int key = g >> 5, cq = g & 31;
            const float4 v = *(const float4*)(src + key * 128 + cq * 4);
            *(float4*)&Ts[key][cq * 4] = v;
        }
        __syncthreads();
#pragma unroll
        for (int p = 0; p < 2; ++p) {
            const int g = p * 256 + tid;
            const int kc = g >> 7, d = g & 127;
            short8 o;
#pragma unroll
            for (int j = 0; j < 8; ++j) o[j] = (short)f2bf(Ts[kc * 8 + j][d]);
            *(short8*)(dst + kc * 1024 + d * 8) = o;
        }
    }
}

// ---------------------------------------------------------------------------
// NT GEMM bf16 MFMA, 128x128 tile, in-block split-K (R9, best known).
// OMODE: 0 = fp32 row-major, 2 = bf16 packed-Q layout
//        ([b][h][qtile32][16 ch][32 q][8] — K-fragment layout for attn).
// ---------------------------------------------------------------------------
template <int OMODE>
__global__ __launch_bounds__(512, 2) void gemm_nt_sk(
    const unsigned short* __restrict__ A,
    const unsigned short* __restrict__ W,
    const float* __restrict__ bias,
    void* __restrict__ Cout, int M, int N, int K, float oscale)
{
    __shared__ __align__(16) unsigned short SMEM[32768];   // 64 KB
    unsigned short* Asb = SMEM;
    unsigned short* Wsb = SMEM + 16384;

    const int tid = threadIdx.x;
    const int g = tid >> 8;
    const int t2 = tid & 255;
    const int lane = tid & 63;
    const int wq = (tid >> 6) & 3;
    const int wm = wq & 1, wn = wq >> 1;
    const int m0 = blockIdx.y * 128, n0 = blockIdx.x * 128;
    const int r0 = t2 >> 2, c0 = t2 & 3;
    const int Kh = K >> 1;

    const unsigned short* Ag = A + (size_t)(m0 + r0) * K + g * Kh + c0 * 8;
    const unsigned short* Wg = W + (size_t)(n0 + r0) * K + g * Kh + c0 * 8;

    f32x4 acc[4][4];
#pragma unroll
    for (int i = 0; i < 4; ++i)
#pragma unroll
        for (int j = 0; j < 4; ++j) acc[i][j] = (f32x4){0.f, 0.f, 0.f, 0.f};

    const int lm = lane & 15, lk = (lane >> 4) * 8;
    unsigned short* As0 = Asb + g * 8192;
    unsigned short* Ws0 = Wsb + g * 8192;

    gl_lds16(Ag,                  As0 + t2 * 8);
    gl_lds16(Ag + (size_t)64 * K, As0 + (t2 + 256) * 8);
    gl_lds16(Wg,                  Ws0 + t2 * 8);
    gl_lds16(Wg + (size_t)64 * K, Ws0 + (t2 + 256) * 8);

    int buf = 0;
    for (int k0 = 0; k0 < Kh; k0 += 32) {
        __syncthreads();
        const int kn = k0 + 32;
        if (kn < Kh) {
            unsigned short* Ad = As0 + (buf ^ 1) * 4096;
            unsigned short* Wd = Ws0 + (buf ^ 1) * 4096;
            gl_lds16(Ag + kn,                  Ad + t2 * 8);
            gl_lds16(Ag + (size_t)64 * K + kn, Ad + (t2 + 256) * 8);
            gl_lds16(Wg + kn,                  Wd + t2 * 8);
            gl_lds16(Wg + (size_t)64 * K + kn, Wd + (t2 + 256) * 8);
        }

        const unsigned short* Ar = As0 + buf * 4096;
        const unsigned short* Wr = Ws0 + buf * 4096;
        short8 a[4], b[4];
#pragma unroll
        for (int i = 0; i < 4; ++i)
            a[i] = *(const short8*)&Ar[(64 * wm + 16 * i + lm) * 32 + lk];
#pragma unroll
        for (int j = 0; j < 4; ++j)
            b[j] = *(const short8*)&Wr[(64 * wn + 16 * j + lm) * 32 + lk];
#pragma unroll
        for (int i = 0; i < 4; ++i)
#pragma unroll
            for (int j = 0; j < 4; ++j)
                acc[i][j] = __builtin_amdgcn_mfma_f32_16x16x32_bf16(a[i], b[j], acc[i][j], 0, 0, 0);
        buf ^= 1;
    }

    float* MRG = (float*)SMEM;
    __syncthreads();
    if (g == 1) {
#pragma unroll
        for (int i = 0; i < 4; ++i)
#pragma unroll
            for (int j = 0; j < 4; ++j) {
                float4 v4;
                v4.x = acc[i][j][0]; v4.y = acc[i][j][1];
                v4.z = acc[i][j][2]; v4.w = acc[i][j][3];
                *(float4*)&MRG[((i * 4 + j) * 256 + wq * 64 + lane) * 4] = v4;
            }
    }
    __syncthreads();
    if (g == 0) {
        float bv[4];
#pragma unroll
        for (int j = 0; j < 4; ++j) bv[j] = bias[n0 + 64 * wn + 16 * j + lm];
#pragma unroll
        for (int i = 0; i < 4; ++i)
#pragma unroll
            for (int j = 0; j < 4; ++j) {
                const float4 v4 = *(const float4*)&MRG[((i * 4 + j) * 256 + wq * 64 + lane) * 4];
                const float s[4] = {v4.x, v4.y, v4.z, v4.w};
#pragma unroll
                for (int reg = 0; reg < 4; ++reg) {
                    const int row = m0 + 64 * wm + 16 * i + 4 * (lane >> 4) + reg;
                    const int col = n0 + 64 * wn + 16 * j + lm;
                    const float v = (acc[i][j][reg] + s[reg] + bv[j]) * oscale;
                    if (OMODE == 0) {
                        ((float*)Cout)[(size_t)row * N + col] = v;
                    } else {
                        // packed-Q: row=(b,s), col=(h,d) -> [(b*16+h)*64 + s/32][d/8][s%32][d%8]
                        const int bb = row >> 11, ss = row & 2047;
                        const int hh = col >> 7, dd = col & 127;
                        const size_t o = (size_t)((bb * 16 + hh) * 64 + (ss >> 5)) * 4096
                                       + (dd >> 3) * 256 + (ss & 31) * 8 + (dd & 7);
                        ((unsigned short*)Cout)[o] = f2bf(v);
                    }
                }
            }
    }
}

// ---------------------------------------------------------------------------
// Flash attention v14: v12 base + QK chain split + setprio MFMA clusters.
// 128-thr blocks (2 key-parity waves, one 32-row q-tile), Q in LDS,
// K/V register-direct. Blocks [2048, 6144): fused wp fp32->bf16 convert.
// ---------------------------------------------------------------------------
__global__ __launch_bounds__(128, 3) void attn_mfma14(
    const unsigned short* __restrict__ Qpk, // [2][16][64][16][32][8] bf16, pre-scaled
    const unsigned short* __restrict__ Kpk, // [8][64][16][32][8] bf16
    const unsigned short* __restrict__ Vpk, // [8][64][4][128][8] bf16
    unsigned short* __restrict__ O,         // [4096][2048] bf16
    const float* __restrict__ wp,           // fused: wp cvt input
    unsigned short* __restrict__ wpb)       // fused: wp cvt output
{
    __shared__ __align__(16) float MRG[4096];   // 16 KB: Q tile / merge / epilogue
    __shared__ float Lsm[64];

    const int tid = threadIdx.x;

    if (blockIdx.x >= 2048) {               // fused wp convert
        const int i = ((blockIdx.x - 2048) * 128 + tid) * 8;
        cvt8(wp, wpb, i);
        return;
    }

    const int lane = tid & 63, pz = tid >> 6;
    const int h2 = lane >> 5, ln = lane & 31;

    // bid&7 = (b,kh): one K/V set per XCD (L2-local). Long q-tiles first.
    const int bid = blockIdx.x;
    const int grp = bid & 7;
    const int idx = bid >> 3;               // [0,256)
    const int b = grp >> 2, kh = grp & 3;
    const int hl = idx & 3;
    const int qt = 63 - (idx >> 2);         // [0,64), descending work
    const int h = kh * 4 + hl;

    const unsigned short* Kbase = Kpk + (size_t)(b * 4 + kh) * 64 * 4096;
    const unsigned short* Vbase = Vpk + (size_t)(b * 4 + kh) * 64 * 4096;
    const int koff = h2 * 256 + ln * 8;     // K fragment lane offset (shorts)
    const int voff = h2 * 1024 + ln * 8;    // V fragment lane offset (shorts)

    // ---- stage Q tile (8 KB) into LDS, fragment layout ----
    unsigned short* QL = (unsigned short*)MRG;
    {
        const unsigned short* qsrc = Qpk + (size_t)((b * 16 + h) * 64 + qt) * 4096;
#pragma unroll
        for (int i = 0; i < 4; ++i)
            gl_lds16(qsrc + (i * 128 + tid) * 8, QL + (i * 128 + pz * 64) * 8);
    }

    f32x16 Ot[4];
#pragma unroll
    for (int mt = 0; mt < 4; ++mt)
#pragma unroll
        for (int r = 0; r < 16; ++r) Ot[mt][r] = 0.f;
    float l_ = 0.f;

    __syncthreads();   // Q staged (vmcnt drained by syncthreads)

    const int q_lo = qt * 32;
    const int qg = q_lo + ln;
    const int q_hi = q_lo + 31;
    const int jmax = qt >> 1;

    for (int j = 0; j <= jmax; ++j) {
        const int t0 = 64 * j + 32 * pz;
        if (t0 > q_hi) continue;     // only pz=1 at j==jmax for even qt

        const unsigned short* Kt = Kbase + (size_t)(2 * j + pz) * 4096;
        const unsigned short* Vt = Vbase + (size_t)(2 * j + pz) * 4096;

        short8 kf[8], vf[8];
#pragma unroll
        for (int ks = 0; ks < 8; ++ks)
            kf[ks] = *(const short8*)(Kt + ks * 512 + koff);
#pragma unroll
        for (int i = 0; i < 8; ++i)
            vf[i] = *(const short8*)(Vt + (i >> 2) * 2048 + (i & 3) * 256 + voff);

        // ---- St = K Q^T, TWO independent 4-deep chains (St0 || St1) ----
        f32x16 St0, St1;
#pragma unroll
        for (int r = 0; r < 16; ++r) { St0[r] = 0.f; St1[r] = 0.f; }
        __builtin_amdgcn_s_setprio(1);
#pragma unroll
        for (int ks = 0; ks < 4; ++ks) {
            const short8 qa = *(const short8*)(QL + ks * 512 + h2 * 256 + ln * 8);
            St0 = __builtin_amdgcn_mfma_f32_32x32x16_bf16(kf[ks], qa, St0, 0, 0, 0);
            const short8 qb = *(const short8*)(QL + (ks + 4) * 512 + h2 * 256 + ln * 8);
            St1 = __builtin_amdgcn_mfma_f32_32x32x16_bf16(kf[ks + 4], qb, St1, 0, 0, 0);
        }
        __builtin_amdgcn_s_setprio(0);

        // ---- P = exp2(s - CAP) with causal mask; row sum ----
        float s_loc = 0.f;
        unsigned Pp[8];
        if (t0 + 31 <= q_lo) {   // wave fully unmasked
#pragma unroll
            for (int p = 0; p < 8; ++p) {
                const float p0 = fexp2(St0[2 * p] + St1[2 * p] - CAP2);
                const float p1 = fexp2(St0[2 * p + 1] + St1[2 * p + 1] - CAP2);
                s_loc += p0 + p1;
                Pp[p] = pack_bf16(p0, p1);
            }
        } else {
#pragma unroll
            for (int p = 0; p < 8; ++p) {
                const int k0 = t0 + (2 * p & 3) + 8 * (2 * p >> 2) + 4 * h2;
                const int k1 = t0 + ((2 * p + 1) & 3) + 8 * ((2 * p + 1) >> 2) + 4 * h2;
                const float p0 = (k0 <= qg) ? fexp2(St0[2 * p] + St1[2 * p] - CAP2) : 0.f;
                const float p1 = (k1 <= qg) ? fexp2(St0[2 * p + 1] + St1[2 * p + 1] - CAP2) : 0.f;
                s_loc += p0 + p1;
                Pp[p] = pack_bf16(p0, p1);
            }
        }
        s_loc += __shfl_xor(s_loc, 32);
        l_ += s_loc;

        // ---- Ot += V P^T (2 k-steps of 16 keys) ----
#pragma unroll
        for (int ks4 = 0; ks4 < 2; ++ks4) {
            const unsigned pa = Pp[4 * ks4 + 0], pb = Pp[4 * ks4 + 1];
            const unsigned pc = Pp[4 * ks4 + 2], pd = Pp[4 * ks4 + 3];
            const unsigned x0 = (unsigned)__shfl_xor((int)(h2 ? pa : pc), 32);
            const unsigned x1 = (unsigned)__shfl_xor((int)(h2 ? pb : pd), 32);
            union { unsigned u[4]; short8 s8; } fr;
            fr.u[0] = h2 ? x0 : pa;
            fr.u[1] = h2 ? x1 : pb;
            fr.u[2] = h2 ? pc : x0;
            fr.u[3] = h2 ? pd : x1;
            __builtin_amdgcn_s_setprio(1);
#pragma unroll
            for (int mt = 0; mt < 4; ++mt)
                Ot[mt] = __builtin_amdgcn_mfma_f32_32x32x16_bf16(vf[ks4 * 4 + mt], fr.s8, Ot[mt], 0, 0, 0);
            __builtin_amdgcn_s_setprio(0);
        }
    }

    // ---- merge key-parity states: plain add (same CAP both halves) ----
    __syncthreads();   // Q reads done; MRG reusable
    if (pz == 1) {
#pragma unroll
        for (int mt = 0; mt < 4; ++mt)
#pragma unroll
            for (int g = 0; g < 4; ++g) {
                float4 v4;
                v4.x = Ot[mt][4 * g + 0]; v4.y = Ot[mt][4 * g + 1];
                v4.z = Ot[mt][4 * g + 2]; v4.w = Ot[mt][4 * g + 3];
                *(float4*)&MRG[lane * 64 + (((mt * 4 + g + lane) & 15) * 4)] = v4;
            }
        Lsm[lane] = l_;
    }
    __syncthreads();
    if (pz == 0) {
        l_ += Lsm[lane];
#pragma unroll
        for (int mt = 0; mt < 4; ++mt)
#pragma unroll
            for (int g = 0; g < 4; ++g) {
                const float4 v4 = *(const float4*)&MRG[lane * 64 + (((mt * 4 + g + lane) & 15) * 4)];
                Ot[mt][4 * g + 0] += v4.x;
                Ot[mt][4 * g + 1] += v4.y;
                Ot[mt][4 * g + 2] += v4.z;
                Ot[mt][4 * g + 3] += v4.w;
            }
    }
    __syncthreads();

    if (pz == 0) {
        unsigned short* Es = (unsigned short*)MRG;
        const float inv = 1.0f / l_;
#pragma unroll
        for (int mt = 0; mt < 4; ++mt)
#pragma unroll
            for (int g = 0; g < 4; ++g) {
                uint2 pk;
                pk.x = pack_bf16(Ot[mt][4 * g + 0] * inv, Ot[mt][4 * g + 1] * inv);
                pk.y = pack_bf16(Ot[mt][4 * g + 2] * inv, Ot[mt][4 * g + 3] * inv);
                const int chunk = (4 * mt + g) ^ (ln & 15);
                *(uint2*)&Es[ln * 128 + chunk * 8 + 4 * h2] = pk;
            }
    }
    __syncthreads();
    if (pz == 0) {
        unsigned short* Es = (unsigned short*)MRG;
#pragma unroll
        for (int pp = 0; pp < 8; ++pp) {
            const int f = pp * 64 + lane;
            const int q = f >> 4, c = f & 15;
            const short8 v = *(const short8*)&Es[q * 128 + ((c ^ (q & 15)) * 8)];
            *(short8*)(O + (size_t)(b * 2048 + q_lo + q) * 2048 + h * 128 + c * 8) = v;
        }
    }
}

// ---------------------------------------------------------------------------
extern "C" void kernel_launch(void* const* d_in, const int* in_sizes, int n_in,
                              void* d_out, int out_size, void* d_ws, size_t ws_size,
                              hipStream_t stream) {
    const float* hs = (const float*)d_in[0];
    const float* k  = (const float*)d_in[1];
    const float* v  = (const float*)d_in[2];
    const float* wq = (const float*)d_in[3];
    const float* bq = (const float*)d_in[4];
    const float* wp = (const float*)d_in[5];
    const float* bp = (const float*)d_in[6];
    float* out = (float*)d_out;

    unsigned short* hsb  = (unsigned short*)d_ws;     // 8,388,608
    unsigned short* wqb  = hsb  + 8388608;            // 4,194,304
    unsigned short* kpk  = wqb  + 4194304;            // 2,097,152
    unsigned short* vpk  = kpk  + 2097152;            // 2,097,152
    unsigned short* qbuf = vpk  + 2097152;            // 8,388,608 (packed Q)
    unsigned short* abuf = qbuf + 8388608;            // 8,388,608
    unsigned short* wpb  = hsb;                       // alias (hs dead after GEMM1)

    prep_all<<<7168, 256, 0, stream>>>(hs, hsb, wq, wqb, k, kpk, v, vpk);

    dim3 gG(16, 32);
    gemm_nt_sk<2><<<gG, 512, 0, stream>>>(hsb, wqb, bq, qbuf, 4096, 2048, 2048, RS2L);
    attn_mfma14<<<6144, 128, 0, stream>>>(qbuf, kpk, vpk, abuf, wp, wpb);
    gemm_nt_sk<0><<<gG, 512, 0, stream>>>(abuf, wpb, bp, out, 4096, 2048, 2048, 1.0f);
}

// Round 10
// 264.620 us; speedup vs baseline: 2.4017x; 1.2124x over previous
//
#include <hip/hip_runtime.h>
#include <math.h>

// B=2, S=2048, H=2048, NH=16, KVH=4, D=128, layer 5.
// GEMMs: mfma_f32_16x16x32_bf16, 128x128 tile, in-block split-K, v16
//   PARALLEL epilogue with STATIC acc indexing (rule-#20 compliant: branch
//   on g, literal acc bases in each branch — R8's runtime-indexed version
//   spilled acc to scratch, 58->352us).
// Attention v12 EXACT (best measured: 60.6us, 3 waves/SIMD, no spill).
//   R9 lesson: the 170-reg budget has no headroom — St0||St1 chain split
//   (+16 regs) spilled (WRITE 24.6->69MB, attn 60->127us). Reverted.
// Launches: prep_all -> GEMM1(packed-Q) -> attn(+wp cvt) -> GEMM2.

#define RSQ128 0.08838834764831845
#define LOG2E  1.4426950408889634
#define RS2L   ((float)(RSQ128 * LOG2E))
#define CAP2   24.0f

typedef __attribute__((ext_vector_type(8))) short short8;    // 8 bf16 = 4 VGPR
typedef __attribute__((ext_vector_type(4))) float f32x4;     // 16x16 C/D
typedef __attribute__((ext_vector_type(16))) float f32x16;   // 32x32 C/D

static __device__ __forceinline__ unsigned short f2bf(float x) {
    union { float f; unsigned u; } v; v.f = x;
    unsigned r = v.u + 0x7FFFu + ((v.u >> 16) & 1u);   // RNE
    return (unsigned short)(r >> 16);
}

static __device__ __forceinline__ unsigned pack_bf16(float lo, float hi) {
#if __has_builtin(__builtin_amdgcn_cvt_pk_bf16_f32)
    return __builtin_bit_cast(unsigned, __builtin_amdgcn_cvt_pk_bf16_f32(lo, hi));
#else
    return (unsigned)f2bf(lo) | ((unsigned)f2bf(hi) << 16);
#endif
}

static __device__ __forceinline__ float fexp2(float x) {
#if __has_builtin(__builtin_amdgcn_exp2f)
    return __builtin_amdgcn_exp2f(x);
#else
    return exp2f(x);
#endif
}

static __device__ __forceinline__ void gl_lds16(const void* g, void* l) {
    __builtin_amdgcn_global_load_lds(
        (const __attribute__((address_space(1))) void*)g,
        (__attribute__((address_space(3))) void*)l, 16, 0, 0);
}

static __device__ __forceinline__ void cvt8(const float* __restrict__ in,
                                            unsigned short* __restrict__ out,
                                            int i) {
    const float4 a = *(const float4*)(in + i);
    const float4 b = *(const float4*)(in + i + 4);
    short8 o;
    o[0] = (short)f2bf(a.x); o[1] = (short)f2bf(a.y);
    o[2] = (short)f2bf(a.z); o[3] = (short)f2bf(a.w);
    o[4] = (short)f2bf(b.x); o[5] = (short)f2bf(b.y);
    o[6] = (short)f2bf(b.z); o[7] = (short)f2bf(b.w);
    *(short8*)(out + i) = o;
}

// ---------------------------------------------------------------------------
// prep_all: one launch for {hs cvt, wq cvt, K prepack, V prepack}.
// blocks [0,4096): hs | [4096,6144): wq | [6144,6656): kprep | [6656,7168): vprep
// ---------------------------------------------------------------------------
__global__ void prep_all(const float* __restrict__ hs, unsigned short* __restrict__ hsb,
                         const float* __restrict__ wq, unsigned short* __restrict__ wqb,
                         const float* __restrict__ K,  unsigned short* __restrict__ Kpk,
                         const float* __restrict__ V,  unsigned short* __restrict__ Vpk)
{
    __shared__ float Ts[32][132];
    const int bid = blockIdx.x, tid = threadIdx.x;

    if (bid < 4096) {                       // hs: 8,388,608 elems
        cvt8(hs, hsb, (bid * 256 + tid) * 8);
        return;
    }
    if (bid < 6144) {                       // wq: 4,194,304 elems
        cvt8(wq, wqb, ((bid - 4096) * 256 + tid) * 8);
        return;
    }
    if (bid < 6656) {                       // kprep: [8][64 tiles]
        const int idx = bid - 6144;
        const int t = idx & 63, bkh = idx >> 6;
        const float* src = K + ((size_t)bkh * 2048 + t * 32) * 128;
        unsigned short* dst = Kpk + ((size_t)bkh * 64 + t) * 4096;
#pragma unroll
        for (int p = 0; p < 2; ++p) {
            const int g = p * 256 + tid;
            const int ch = g >> 5, key = g & 31;
            const float4 a = *(const float4*)(src + key * 128 + ch * 8);
            const float4 b = *(const float4*)(src + key * 128 + ch * 8 + 4);
            short8 o;
            o[0] = (short)f2bf(a.x); o[1] = (short)f2bf(a.y);
            o[2] = (short)f2bf(a.z); o[3] = (short)f2bf(a.w);
            o[4] = (short)f2bf(b.x); o[5] = (short)f2bf(b.y);
            o[6] = (short)f2bf(b.z); o[7] = (short)f2bf(b.w);
            *(short8*)(dst + ch * 256 + key * 8) = o;
        }
        return;
    }
    {                                       // vprep: [8][64 tiles]
        const int idx = bid - 6656;
        const int t = idx & 63, bkh = idx >> 6;
        const float* src = V + ((size_t)bkh * 2048 + t * 32) * 128;
        unsigned short* dst = Vpk + ((size_t)bkh * 64 + t) * 4096;
#pragma unroll
        for (int p = 0; p < 4; ++p) {
            const int g = p * 256 + tid;
            const int key = g >> 5, cq = g & 31;
            const float4 v = *(const float4*)(src + key * 128 + cq * 4);
            *(float4*)&Ts[key][cq * 4] = v;
        }
        __syncthreads();
#pragma unroll
        for (int p = 0; p < 2; ++p) {
            const int g = p * 256 + tid;
            const int kc = g >> 7, d = g & 127;
            short8 o;
#pragma unroll
            for (int j = 0; j < 8; ++j) o[j] = (short)f2bf(Ts[kc * 8 + j][d]);
            *(short8*)(dst + kc * 1024 + d * 8) = o;
        }
    }
}

// ---------------------------------------------------------------------------
// NT GEMM bf16 MFMA, 128x128 tile, in-block split-K, parallel static epilogue.
// OMODE: 0 = fp32 row-major, 2 = bf16 packed-Q layout
//        ([b][h][qtile32][16 ch][32 q][8] — K-fragment layout for attn).
// ---------------------------------------------------------------------------
template <int OMODE>
__global__ __launch_bounds__(512, 2) void gemm_nt_sk(
    const unsigned short* __restrict__ A,
    const unsigned short* __restrict__ W,
    const float* __restrict__ bias,
    void* __restrict__ Cout, int M, int N, int K, float oscale)
{
    __shared__ __align__(16) unsigned short SMEM[32768];   // 64 KB
    unsigned short* Asb = SMEM;
    unsigned short* Wsb = SMEM + 16384;

    const int tid = threadIdx.x;
    const int g = tid >> 8;
    const int t2 = tid & 255;
    const int lane = tid & 63;
    const int wq = (tid >> 6) & 3;
    const int wm = wq & 1, wn = wq >> 1;
    const int m0 = blockIdx.y * 128, n0 = blockIdx.x * 128;
    const int r0 = t2 >> 2, c0 = t2 & 3;
    const int Kh = K >> 1;

    const unsigned short* Ag = A + (size_t)(m0 + r0) * K + g * Kh + c0 * 8;
    const unsigned short* Wg = W + (size_t)(n0 + r0) * K + g * Kh + c0 * 8;

    f32x4 acc[4][4];
#pragma unroll
    for (int i = 0; i < 4; ++i)
#pragma unroll
        for (int j = 0; j < 4; ++j) acc[i][j] = (f32x4){0.f, 0.f, 0.f, 0.f};

    const int lm = lane & 15, lk = (lane >> 4) * 8;
    unsigned short* As0 = Asb + g * 8192;
    unsigned short* Ws0 = Wsb + g * 8192;

    gl_lds16(Ag,                  As0 + t2 * 8);
    gl_lds16(Ag + (size_t)64 * K, As0 + (t2 + 256) * 8);
    gl_lds16(Wg,                  Ws0 + t2 * 8);
    gl_lds16(Wg + (size_t)64 * K, Ws0 + (t2 + 256) * 8);

    int buf = 0;
    for (int k0 = 0; k0 < Kh; k0 += 32) {
        __syncthreads();
        const int kn = k0 + 32;
        if (kn < Kh) {
            unsigned short* Ad = As0 + (buf ^ 1) * 4096;
            unsigned short* Wd = Ws0 + (buf ^ 1) * 4096;
            gl_lds16(Ag + kn,                  Ad + t2 * 8);
            gl_lds16(Ag + (size_t)64 * K + kn, Ad + (t2 + 256) * 8);
            gl_lds16(Wg + kn,                  Wd + t2 * 8);
            gl_lds16(Wg + (size_t)64 * K + kn, Wd + (t2 + 256) * 8);
        }

        const unsigned short* Ar = As0 + buf * 4096;
        const unsigned short* Wr = Ws0 + buf * 4096;
        short8 a[4], b[4];
#pragma unroll
        for (int i = 0; i < 4; ++i)
            a[i] = *(const short8*)&Ar[(64 * wm + 16 * i + lm) * 32 + lk];
#pragma unroll
        for (int j = 0; j < 4; ++j)
            b[j] = *(const short8*)&Wr[(64 * wn + 16 * j + lm) * 32 + lk];
#pragma unroll
        for (int i = 0; i < 4; ++i)
#pragma unroll
            for (int j = 0; j < 4; ++j)
                acc[i][j] = __builtin_amdgcn_mfma_f32_16x16x32_bf16(a[i], b[j], acc[i][j], 0, 0, 0);
        buf ^= 1;
    }

    // ---- v16 parallel split-K epilogue, STATIC indices per branch:
    //      g=0 publishes acc[2..3] -> MRG[0..8192), finalizes rows i=0,1;
    //      g=1 publishes acc[0..1] -> MRG[8192..), finalizes rows i=2,3.
    float* MRG = (float*)SMEM;   // 16384 floats = 64 KB
    __syncthreads();
    if (g == 0) {
#pragma unroll
        for (int ii = 0; ii < 2; ++ii)
#pragma unroll
            for (int j = 0; j < 4; ++j) {
                float4 v4;
                v4.x = acc[2 + ii][j][0]; v4.y = acc[2 + ii][j][1];
                v4.z = acc[2 + ii][j][2]; v4.w = acc[2 + ii][j][3];
                *(float4*)&MRG[((ii * 4 + j) * 256 + wq * 64 + lane) * 4] = v4;
            }
    } else {
#pragma unroll
        for (int ii = 0; ii < 2; ++ii)
#pragma unroll
            for (int j = 0; j < 4; ++j) {
                float4 v4;
                v4.x = acc[ii][j][0]; v4.y = acc[ii][j][1];
                v4.z = acc[ii][j][2]; v4.w = acc[ii][j][3];
                *(float4*)&MRG[8192 + ((ii * 4 + j) * 256 + wq * 64 + lane) * 4] = v4;
            }
    }
    __syncthreads();
    {
        float bv[4];
#pragma unroll
        for (int j = 0; j < 4; ++j) bv[j] = bias[n0 + 64 * wn + 16 * j + lm];
        if (g == 0) {
            // finalize rows i = 0,1 (own acc[0..1] + g1's half at MRG+8192)
#pragma unroll
            for (int ii = 0; ii < 2; ++ii)
#pragma unroll
                for (int j = 0; j < 4; ++j) {
                    const float4 v4 = *(const float4*)&MRG[8192 + ((ii * 4 + j) * 256 + wq * 64 + lane) * 4];
                    const float s[4] = {v4.x, v4.y, v4.z, v4.w};
#pragma unroll
                    for (int reg = 0; reg < 4; ++reg) {
                        const int row = m0 + 64 * wm + 16 * ii + 4 * (lane >> 4) + reg;
                        const int col = n0 + 64 * wn + 16 * j + lm;
                        const float v = (acc[ii][j][reg] + s[reg] + bv[j]) * oscale;
                        if (OMODE == 0) {
                            ((float*)Cout)[(size_t)row * N + col] = v;
                        } else {
                            const int bb = row >> 11, ss = row & 2047;
                            const int hh = col >> 7, dd = col & 127;
                            const size_t o = (size_t)((bb * 16 + hh) * 64 + (ss >> 5)) * 4096
                                           + (dd >> 3) * 256 + (ss & 31) * 8 + (dd & 7);
                            ((unsigned short*)Cout)[o] = f2bf(v);
                        }
                    }
                }
        } else {
            // finalize rows i = 2,3 (own acc[2..3] + g0's half at MRG+0)
#pragma unroll
            for (int ii = 0; ii < 2; ++ii)
#pragma unroll
                for (int j = 0; j < 4; ++j) {
                    const float4 v4 = *(const float4*)&MRG[((ii * 4 + j) * 256 + wq * 64 + lane) * 4];
                    const float s[4] = {v4.x, v4.y, v4.z, v4.w};
#pragma unroll
                    for (int reg = 0; reg < 4; ++reg) {
                        const int row = m0 + 64 * wm + 16 * (2 + ii) + 4 * (lane >> 4) + reg;
                        const int col = n0 + 64 * wn + 16 * j + lm;
                        const float v = (acc[2 + ii][j][reg] + s[reg] + bv[j]) * oscale;
                        if (OMODE == 0) {
                            ((float*)Cout)[(size_t)row * N + col] = v;
                        } else {
                            const int bb = row >> 11, ss = row & 2047;
                            const int hh = col >> 7, dd = col & 127;
                            const size_t o = (size_t)((bb * 16 + hh) * 64 + (ss >> 5)) * 4096
                                           + (dd >> 3) * 256 + (ss & 31) * 8 + (dd & 7);
                            ((unsigned short*)Cout)[o] = f2bf(v);
                        }
                    }
                }
        }
    }
}

// ---------------------------------------------------------------------------
// Flash attention v12 (EXACT R6 version, best measured): 128-thr blocks
// (2 key-parity waves, one 32-row q-tile), Q in LDS, K/V register-direct.
// Blocks [2048, 6144): fused wp fp32->bf16 convert.
// ---------------------------------------------------------------------------
__global__ __launch_bounds__(128, 3) void attn_mfma12(
    const unsigned short* __restrict__ Qpk, // [2][16][64][16][32][8] bf16, pre-scaled
    const unsigned short* __restrict__ Kpk, // [8][64][16][32][8] bf16
    const unsigned short* __restrict__ Vpk, // [8][64][4][128][8] bf16
    unsigned short* __restrict__ O,         // [4096][2048] bf16
    const float* __restrict__ wp,           // fused: wp cvt input
    unsigned short* __restrict__ wpb)       // fused: wp cvt output
{
    __shared__ __align__(16) float MRG[4096];   // 16 KB: Q tile / merge / epilogue
    __shared__ float Lsm[64];

    const int tid = threadIdx.x;

    if (blockIdx.x >= 2048) {               // fused wp convert
        const int i = ((blockIdx.x - 2048) * 128 + tid) * 8;
        cvt8(wp, wpb, i);
        return;
    }

    const int lane = tid & 63, pz = tid >> 6;
    const int h2 = lane >> 5, ln = lane & 31;

    // bid&7 = (b,kh): one K/V set per XCD (L2-local). Long q-tiles first.
    const int bid = blockIdx.x;
    const int grp = bid & 7;
    const int idx = bid >> 3;               // [0,256)
    const int b = grp >> 2, kh = grp & 3;
    const int hl = idx & 3;
    const int qt = 63 - (idx >> 2);         // [0,64), descending work
    const int h = kh * 4 + hl;

    const unsigned short* Kbase = Kpk + (size_t)(b * 4 + kh) * 64 * 4096;
    const unsigned short* Vbase = Vpk + (size_t)(b * 4 + kh) * 64 * 4096;
    const int koff = h2 * 256 + ln * 8;     // K fragment lane offset (shorts)
    const int voff = h2 * 1024 + ln * 8;    // V fragment lane offset (shorts)

    // ---- stage Q tile (8 KB) into LDS, fragment layout ----
    unsigned short* QL = (unsigned short*)MRG;
    {
        const unsigned short* qsrc = Qpk + (size_t)((b * 16 + h) * 64 + qt) * 4096;
#pragma unroll
        for (int i = 0; i < 4; ++i)
            gl_lds16(qsrc + (i * 128 + tid) * 8, QL + (i * 128 + pz * 64) * 8);
    }

    f32x16 Ot[4];
#pragma unroll
    for (int mt = 0; mt < 4; ++mt)
#pragma unroll
        for (int r = 0; r < 16; ++r) Ot[mt][r] = 0.f;
    float l_ = 0.f;

    __syncthreads();   // Q staged (vmcnt drained by syncthreads)

    const int q_lo = qt * 32;
    const int qg = q_lo + ln;
    const int q_hi = q_lo + 31;
    const int jmax = qt >> 1;

    for (int j = 0; j <= jmax; ++j) {
        const int t0 = 64 * j + 32 * pz;
        if (t0 > q_hi) continue;     // only pz=1 at j==jmax for even qt

        const unsigned short* Kt = Kbase + (size_t)(2 * j + pz) * 4096;
        const unsigned short* Vt = Vbase + (size_t)(2 * j + pz) * 4096;

        short8 kf[8], vf[8];
#pragma unroll
        for (int ks = 0; ks < 8; ++ks)
            kf[ks] = *(const short8*)(Kt + ks * 512 + koff);
#pragma unroll
        for (int i = 0; i < 8; ++i)
            vf[i] = *(const short8*)(Vt + (i >> 2) * 2048 + (i & 3) * 256 + voff);

        // ---- St = K Q^T : col=q=ln, rows=key(0..31); Q from LDS ----
        f32x16 St;
#pragma unroll
        for (int r = 0; r < 16; ++r) St[r] = 0.f;
#pragma unroll
        for (int ks = 0; ks < 8; ++ks) {
            const short8 qf = *(const short8*)(QL + ks * 512 + h2 * 256 + ln * 8);
            St = __builtin_amdgcn_mfma_f32_32x32x16_bf16(kf[ks], qf, St, 0, 0, 0);
        }

        // ---- P = exp2(s - CAP) with causal mask; row sum ----
        float s_loc = 0.f;
        unsigned Pp[8];
        if (t0 + 31 <= q_lo) {   // wave fully unmasked
#pragma unroll
            for (int p = 0; p < 8; ++p) {
                const float p0 = fexp2(St[2 * p] - CAP2);
                const float p1 = fexp2(St[2 * p + 1] - CAP2);
                s_loc += p0 + p1;
                Pp[p] = pack_bf16(p0, p1);
            }
        } else {
#pragma unroll
            for (int p = 0; p < 8; ++p) {
                const int k0 = t0 + (2 * p & 3) + 8 * (2 * p >> 2) + 4 * h2;
                const int k1 = t0 + ((2 * p + 1) & 3) + 8 * ((2 * p + 1) >> 2) + 4 * h2;
                const float p0 = (k0 <= qg) ? fexp2(St[2 * p] - CAP2) : 0.f;
                const float p1 = (k1 <= qg) ? fexp2(St[2 * p + 1] - CAP2) : 0.f;
                s_loc += p0 + p1;
                Pp[p] = pack_bf16(p0, p1);
            }
        }
        s_loc += __shfl_xor(s_loc, 32);
        l_ += s_loc;

        // ---- Ot += V P^T (2 k-steps of 16 keys) ----
#pragma unroll
        for (int ks4 = 0; ks4 < 2; ++ks4) {
            const unsigned pa = Pp[4 * ks4 + 0], pb = Pp[4 * ks4 + 1];
            const unsigned pc = Pp[4 * ks4 + 2], pd = Pp[4 * ks4 + 3];
            const unsigned x0 = (unsigned)__shfl_xor((int)(h2 ? pa : pc), 32);
            const unsigned x1 = (unsigned)__shfl_xor((int)(h2 ? pb : pd), 32);
            union { unsigned u[4]; short8 s8; } fr;
            fr.u[0] = h2 ? x0 : pa;
            fr.u[1] = h2 ? x1 : pb;
            fr.u[2] = h2 ? pc : x0;
            fr.u[3] = h2 ? pd : x1;
#pragma unroll
            for (int mt = 0; mt < 4; ++mt)
                Ot[mt] = __builtin_amdgcn_mfma_f32_32x32x16_bf16(vf[ks4 * 4 + mt], fr.s8, Ot[mt], 0, 0, 0);
        }
    }

    // ---- merge key-parity states: plain add (same CAP both halves) ----
    __syncthreads();   // Q reads done; MRG reusable
    if (pz == 1) {
#pragma unroll
        for (int mt = 0; mt < 4; ++mt)
#pragma unroll
            for (int g = 0; g < 4; ++g) {
                float4 v4;
                v4.x = Ot[mt][4 * g + 0]; v4.y = Ot[mt][4 * g + 1];
                v4.z = Ot[mt][4 * g + 2]; v4.w = Ot[mt][4 * g + 3];
                *(float4*)&MRG[lane * 64 + (((mt * 4 + g + lane) & 15) * 4)] = v4;
            }
        Lsm[lane] = l_;
    }
    __syncthreads();
    if (pz == 0) {
        l_ += Lsm[lane];
#pragma unroll
        for (int mt = 0; mt < 4; ++mt)
#pragma unroll
            for (int g = 0; g < 4; ++g) {
                const float4 v4 = *(const float4*)&MRG[lane * 64 + (((mt * 4 + g + lane) & 15) * 4)];
                Ot[mt][4 * g + 0] += v4.x;
                Ot[mt][4 * g + 1] += v4.y;
                Ot[mt][4 * g + 2] += v4.z;
                Ot[mt][4 * g + 3] += v4.w;
            }
    }
    __syncthreads();

    if (pz == 0) {
        unsigned short* Es = (unsigned short*)MRG;
        const float inv = 1.0f / l_;
#pragma unroll
        for (int mt = 0; mt < 4; ++mt)
#pragma unroll
            for (int g = 0; g < 4; ++g) {
                uint2 pk;
                pk.x = pack_bf16(Ot[mt][4 * g + 0] * inv, Ot[mt][4 * g + 1] * inv);
                pk.y = pack_bf16(Ot[mt][4 * g + 2] * inv, Ot[mt][4 * g + 3] * inv);
                const int chunk = (4 * mt + g) ^ (ln & 15);
                *(uint2*)&Es[ln * 128 + chunk * 8 + 4 * h2] = pk;
            }
    }
    __syncthreads();
    if (pz == 0) {
        unsigned short* Es = (unsigned short*)MRG;
#pragma unroll
        for (int pp = 0; pp < 8; ++pp) {
            const int f = pp * 64 + lane;
            const int q = f >> 4, c = f & 15;
            const short8 v = *(const short8*)&Es[q * 128 + ((c ^ (q & 15)) * 8)];
            *(short8*)(O + (size_t)(b * 2048 + q_lo + q) * 2048 + h * 128 + c * 8) = v;
        }
    }
}

// ---------------------------------------------------------------------------
extern "C" void kernel_launch(void* const* d_in, const int* in_sizes, int n_in,
                              void* d_out, int out_size, void* d_ws, size_t ws_size,
                              hipStream_t stream) {
    const float* hs = (const float*)d_in[0];
    const float* k  = (const float*)d_in[1];
    const float* v  = (const float*)d_in[2];
    const float* wq = (const float*)d_in[3];
    const float* bq = (const float*)d_in[4];
    const float* wp = (const float*)d_in[5];
    const float* bp = (const float*)d_in[6];
    float* out = (float*)d_out;

    unsigned short* hsb  = (unsigned short*)d_ws;     // 8,388,608
    unsigned short* wqb  = hsb  + 8388608;            // 4,194,304
    unsigned short* kpk  = wqb  + 4194304;            // 2,097,152
    unsigned short* vpk  = kpk  + 2097152;            // 2,097,152
    unsigned short* qbuf = vpk  + 2097152;            // 8,388,608 (packed Q)
    unsigned short* abuf = qbuf + 8388608;            // 8,388,608
    unsigned short* wpb  = hsb;                       // alias (hs dead after GEMM1)

    prep_all<<<7168, 256, 0, stream>>>(hs, hsb, wq, wqb, k, kpk, v, vpk);

    dim3 gG(16, 32);
    gemm_nt_sk<2><<<gG, 512, 0, stream>>>(hsb, wqb, bq, qbuf, 4096, 2048, 2048, RS2L);
    attn_mfma12<<<6144, 128, 0, stream>>>(qbuf, kpk, vpk, abuf, wp, wpb);
    gemm_nt_sk<0><<<gG, 512, 0, stream>>>(abuf, wpb, bp, out, 4096, 2048, 2048, 1.0f);
}